// Round 12
// baseline (59.333 us; speedup 1.0000x reference)
//
#include <hip/hip_runtime.h>
#include <math.h>

#define LMAX 30.0f
typedef unsigned long long ull;
typedef unsigned int u32;

__device__ __forceinline__ float clip30(float x) { return fminf(fmaxf(x, -LMAX), LMAX); }
__device__ __forceinline__ float cnop(float x, float y) {
    x = clip30(x); y = clip30(y);
    const float m = fminf(fabsf(x), fabsf(y));
    const unsigned sg = (__float_as_uint(x) ^ __float_as_uint(y)) & 0x80000000u;
    return __uint_as_float(__float_as_uint(m) | sg);
}

#define SWZF(x, PAT) __int_as_float(__builtin_amdgcn_ds_swizzle(__float_as_int(x), (PAT)))

template<int CTRL>
__device__ __forceinline__ int dppi(int x) {
    return __builtin_amdgcn_update_dpp(x, x, CTRL, 0xF, 0xF, false);
}
template<int CTRL>
__device__ __forceinline__ float dppf(float x) {
    return __int_as_float(dppi<CTRL>(__float_as_int(x)));
}
#define CTL_XOR8 0x128  /* row_ror:8 == xor-8 within 16-lane rows */
#define CTL_XOR2 0x4E   /* quad_perm [2,3,0,1] */
#define CTL_XOR1 0xB1   /* quad_perm [1,0,3,2] */

// lane^32 / lane^16 partners via permlane swaps (VALU, no DS)
#if __has_builtin(__builtin_amdgcn_permlane32_swap)
typedef int v2i_ __attribute__((ext_vector_type(2)));
__device__ __forceinline__ int swap32i(int x) {
    v2i_ r = __builtin_amdgcn_permlane32_swap(x, x, false, false);
    return (r[0] != x) ? r[0] : r[1];
}
#else
__device__ __forceinline__ int swap32i(int x) {
    int a = x, b = x;
    asm volatile("v_permlane32_swap_b32 %0, %1" : "+v"(a), "+v"(b));
    return (a != x) ? a : b;
}
#endif
#if __has_builtin(__builtin_amdgcn_permlane16_swap)
typedef int v2j_ __attribute__((ext_vector_type(2)));
__device__ __forceinline__ int swap16i(int x) {
    v2j_ r = __builtin_amdgcn_permlane16_swap(x, x, false, false);
    return (r[0] != x) ? r[0] : r[1];
}
#else
__device__ __forceinline__ int swap16i(int x) { return __builtin_amdgcn_ds_swizzle(x, 0x401F); }
#endif
__device__ __forceinline__ float swap32f(float x) { return __int_as_float(swap32i(__float_as_int(x))); }
__device__ __forceinline__ float swap16f(float x) { return __int_as_float(swap16i(__float_as_int(x))); }

__device__ __forceinline__ float gfb(float v, int a) {
    return __int_as_float(__builtin_amdgcn_ds_bpermute(a, __float_as_int(v)));
}
__device__ __forceinline__ u32 gub(u32 v, int a) {
    return (u32)__builtin_amdgcn_ds_bpermute(a, (int)v);
}

// polar encode folds
__device__ __forceinline__ u32 enc2(u32 w)  { w ^= (w >> 1) & 0x1u; return w; }
__device__ __forceinline__ u32 enc4(u32 w)  { w ^= (w >> 1) & 0x5u; w ^= (w >> 2) & 0x3u; return w; }
__device__ __forceinline__ u32 enc8(u32 w)  { w ^= (w >> 1) & 0x55u; w ^= (w >> 2) & 0x33u;
                                              w ^= (w >> 4) & 0x0fu; return w; }
__device__ __forceinline__ u32 enc16(u32 w) { w ^= (w >> 1) & 0x5555u; w ^= (w >> 2) & 0x3333u;
                                              w ^= (w >> 4) & 0x0f0fu; w ^= (w >> 8) & 0x00ffu; return w; }
__device__ __forceinline__ u32 enc32(u32 w) { w ^= (w >> 1) & 0x55555555u; w ^= (w >> 2) & 0x33333333u;
                                              w ^= (w >> 4) & 0x0f0f0f0fu; w ^= (w >> 8) & 0x00ff00ffu;
                                              w ^= (w >> 16) & 0x0000ffffu; return w; }

// ---- 1 decoder/wave, 4 rows. pos = lane&15, row p = lane>>4.
// Distributed over rows (stride 4): C[16], S5[8], S4[4], S3[2].
// Replicated: R2[4], R1[2]. uhat: u32 per 32-leaf half. Deferred clone maps
// mS3/mS4/mS5 (1 word each) instead of physical segment clones.
struct Dec {
    float C[16];
    float S5[8], S4[4], S3[2], R2[4], R1[2];
    float pm;
    u32 uhPrev, uhCur;
    int rF;
    int mS5, mS4, mS3;
    int p, pos, gbase, A0, idx0;
    u32 upB;
    bool isUp;
};

__device__ __forceinline__ void f6(Dec& s) {
    #pragma unroll
    for (int k = 0; k < 8; ++k) s.S5[k] = cnop(s.C[k], s.C[k + 8]);
}
__device__ __forceinline__ void g6p(Dec& s) {   // head of half 1
    const u32 ub = enc32(s.uhPrev);
    #pragma unroll
    for (int k = 0; k < 8; ++k) {
        const int u = (ub >> (s.p + 4 * k)) & 1;
        s.S5[k] = u ? (s.C[k + 8] - s.C[k]) : (s.C[k + 8] + s.C[k]);
    }
}
__device__ __forceinline__ void f5(Dec& s) {
    #pragma unroll
    for (int k = 0; k < 4; ++k) s.S4[k] = cnop(s.S5[k], s.S5[k + 4]);
}
// L == 16 only: deferred S5 read through mS5; writes S4 fresh
__device__ __forceinline__ void g5l16(Dec& s) {
    const u32 ub = enc16(s.uhCur & 0xffffu);
    const int am = (s.mS5 | s.gbase) << 2;
    #pragma unroll
    for (int k = 0; k < 4; ++k) {
        const float x = gfb(s.S5[k], am), y = gfb(s.S5[k + 4], am);
        const int u = (ub >> (s.p + 4 * k)) & 1;
        s.S4[k] = u ? (y - x) : (y + x);
    }
    s.mS4 = s.pos;
}
__device__ __forceinline__ void f4(Dec& s) {
    s.S3[0] = cnop(s.S4[0], s.S4[2]); s.S3[1] = cnop(s.S4[1], s.S4[3]);
}
// L in {8,24}: deferred S4 read; writes S3 fresh
template<int L> __device__ __forceinline__ void g4l(Dec& s) {
    const u32 ub = enc8((s.uhCur >> (L - 8)) & 0xffu);
    const int am = (s.mS4 | s.gbase) << 2;
    #pragma unroll
    for (int k = 0; k < 2; ++k) {
        const float x = gfb(s.S4[k], am), y = gfb(s.S4[k + 2], am);
        const int u = (ub >> (s.p + 4 * k)) & 1;
        s.S3[k] = u ? (y - x) : (y + x);
    }
    s.mS3 = s.pos;
}
// replicate per-row value v0 = seg2[p] to R2[0..3] on every lane
__device__ __forceinline__ void repl2(Dec& s, float v0) {
    const float t1 = swap16f(v0);
    const float lo = (s.p & 1) ? t1 : v0;
    const float hi = (s.p & 1) ? v0 : t1;
    const float lo2 = swap32f(lo);
    const float hi2 = swap32f(hi);
    s.R2[0] = (s.p < 2) ? lo : lo2; s.R2[1] = (s.p < 2) ? hi : hi2;
    s.R2[2] = (s.p < 2) ? lo2 : lo; s.R2[3] = (s.p < 2) ? hi2 : hi;
}
__device__ __forceinline__ void f3r(Dec& s) {
    repl2(s, cnop(s.S3[0], s.S3[1]));
}
// L in {4,12,20,28}: deferred S3 read
template<int L> __device__ __forceinline__ void g3rl(Dec& s) {
    const u32 ub = enc4((s.uhCur >> (L - 4)) & 0xfu);
    const int am = (s.mS3 | s.gbase) << 2;
    const float x0 = gfb(s.S3[0], am), x1 = gfb(s.S3[1], am);
    const int u = (ub >> s.p) & 1;
    repl2(s, u ? (x1 - x0) : (x1 + x0));
}
__device__ __forceinline__ void f2(Dec& s) {
    s.R1[0] = cnop(s.R2[0], s.R2[2]); s.R1[1] = cnop(s.R2[1], s.R2[3]);
}
template<int L> __device__ __forceinline__ void g2l(Dec& s) {
    const u32 ub = enc2((s.uhCur >> (L - 2)) & 3u);
    s.R1[0] = (ub & 1) ? (s.R2[2] - s.R2[0]) : (s.R2[2] + s.R2[0]);
    s.R1[1] = (ub & 2) ? (s.R2[3] - s.R2[1]) : (s.R2[3] + s.R2[1]);
}

// leaf: decision + pm + distributed stable rank (4 keys/lane, swap32+swap16
// reduce) + ballot-derived clone source + clone (pm/uh/R1/R2 direct, maps).
template<int L, int CLONEMODE>   // 0 never, 1 always, 2 only h==0
__device__ __forceinline__ void leafR(Dec& s, float l0, int h) {
    s.uhCur |= s.upB << L;
    const float l = clip30(l0);
    const float tail = log1pf(expf(-fabsf(l)));
    s.pm += (s.isUp ? fmaxf(l, 0.0f) : fmaxf(-l, 0.0f)) + tail;
    int r = 0;
    {
        const u32 pmB = __float_as_uint(s.pm);
        #pragma unroll
        for (int k = 0; k < 4; ++k) {
            const u32 pmj = (u32)__builtin_amdgcn_ds_bpermute(s.A0 + 4 * k, __float_as_int(s.pm));
            r += ((pmj < pmB) || (pmj == pmB && (s.idx0 + k) < s.pos)) ? 1 : 0;
        }
    }
    r += swap32i(r);
    r += swap16i(r);
    s.rF = r;
    if constexpr (CLONEMODE != 0) {
        if (CLONEMODE == 1 || h == 0) {
            // src = own-row lane holding rank (pos&7): 8 ballots + select
            const ull b0 = __ballot(r == 0), b1 = __ballot(r == 1);
            const ull b2 = __ballot(r == 2), b3 = __ballot(r == 3);
            const ull b4 = __ballot(r == 4), b5 = __ballot(r == 5);
            const ull b6 = __ballot(r == 6), b7 = __ballot(r == 7);
            const ull t0 = (s.pos & 1) ? b1 : b0;
            const ull t1 = (s.pos & 1) ? b3 : b2;
            const ull t2 = (s.pos & 1) ? b5 : b4;
            const ull t3 = (s.pos & 1) ? b7 : b6;
            const ull u0 = (s.pos & 2) ? t1 : t0;
            const ull u1 = (s.pos & 2) ? t3 : t2;
            const ull bb = (s.pos & 4) ? u1 : u0;
            const u32 win = (u32)(bb >> s.gbase) & 0xFFFFu;
            const int ga = (((int)__builtin_ctz(win)) | s.gbase) << 2;
            s.pm = gfb(s.pm, ga);
            s.uhCur = gub(s.uhCur, ga);
            if (h != 0) s.uhPrev = gub(s.uhPrev, ga);
            if constexpr ((L & 1) == 0) {
                s.R1[0] = gfb(s.R1[0], ga); s.R1[1] = gfb(s.R1[1], ga);
            }
            if constexpr ((L & 2) == 0) {
                #pragma unroll
                for (int e = 0; e < 4; ++e) s.R2[e] = gfb(s.R2[e], ga);
            }
            if constexpr ((L & 4) == 0) s.mS3 = __builtin_amdgcn_ds_bpermute(ga, s.mS3);
            if constexpr ((L & 8) == 0) s.mS4 = __builtin_amdgcn_ds_bpermute(ga, s.mS4);
            if constexpr ((L & 16) == 0) s.mS5 = __builtin_amdgcn_ds_bpermute(ga, s.mS5);
        }
    }
}

template<int J> __device__ __forceinline__ void evenL(Dec& s, int h) {
    constexpr int t = __builtin_ctz(J);   // J even, 2..30 -> t in 1..4
    if constexpr (t == 4) { g5l16(s); f4(s); s.mS3 = s.pos; }
    if constexpr (t == 3) { g4l<J>(s); }
    if constexpr (t >= 3) { f3r(s); }
    if constexpr (t == 2) { g3rl<J>(s); }
    if constexpr (t >= 2) { f2(s); }
    if constexpr (t == 1) { g2l<J>(s); }
    const float l0 = cnop(s.R1[0], s.R1[1]);
    leafR<J, 1>(s, l0, h);
}
template<int J> __device__ __forceinline__ void oddL(Dec& s, int h) {
    const int ug = (int)((s.uhCur >> (J - 1)) & 1u);
    const float l0 = ug ? (s.R1[1] - s.R1[0]) : (s.R1[1] + s.R1[0]);
    leafR<J, (J == 31 ? 2 : 1)>(s, l0, h);
}
template<int J> __device__ __forceinline__ void pairs(Dec& s, int h) {
    evenL<J>(s, h);
    oddL<J + 1>(s, h);
    if constexpr (J + 2 <= 30) pairs<J + 2>(s, h);
}

#define RLF(x, J) __uint_as_float((u32)__builtin_amdgcn_readlane(__float_as_int(x), (J)))

__global__ __launch_bounds__(64) void scl_kernel(const float* __restrict__ in,
                                                 float* __restrict__ out) {
    __shared__ float ch6s[64];
    const int lane = threadIdx.x;

    Dec s;
    s.pos = lane & 15;
    s.p = lane >> 4;
    s.gbase = lane & 48;
    s.isUp = (lane & 8) != 0;
    s.upB = (u32)((lane >> 3) & 1);
    s.idx0 = s.p << 2;
    s.A0 = (s.gbase | (s.p << 2)) << 2;
    s.uhPrev = 0; s.uhCur = 0; s.rF = 0;

    const size_t base = (size_t)blockIdx.x * 128;
    const float a = -in[base + lane];
    const float c = -in[base + 64 + lane];
    ch6s[lane] = a + c;                 // stage-6 right-subtree llr (u=0 g)
    __syncthreads();
    #pragma unroll
    for (int k = 0; k < 16; ++k) s.C[k] = ch6s[s.p + 4 * k];

    // ---- frozen half (leaves 0..63): all paths identical, u == 0; butterfly
    float v = cnop(a, c);
    { const float o = swap32f(v);            v = (lane & 32) ? (o + v) : cnop(v, o); }
    { const float o = swap16f(v);            v = (lane & 16) ? (o + v) : cnop(v, o); }
    { const float o = dppf<CTL_XOR8>(v);     v = (lane & 8)  ? (o + v) : cnop(v, o); }
    { const float o = SWZF(v, 0x101F);       v = (lane & 4)  ? (o + v) : cnop(v, o); }
    { const float o = dppf<CTL_XOR2>(v);     v = (lane & 2)  ? (o + v) : cnop(v, o); }
    { const float o = dppf<CTL_XOR1>(v);     v = (lane & 1)  ? (o + v) : cnop(v, o); }
    const float spf = fmaxf(-clip30(v), 0.0f) + log1pf(expf(-fabsf(clip30(v))));

    // exact sequential pm accumulation (reference FP order)
    s.pm = ((s.pos == 0) || (s.pos == 8)) ? 0.0f : LMAX;
    #pragma unroll
    for (int j = 0; j < 64; ++j) s.pm += RLF(spf, j);

    // ---- info half: two 32-leaf halves sharing one unrolled body ----
    #pragma unroll 1
    for (int h = 0; h < 2; ++h) {
        if (h == 0) f6(s); else g6p(s);    // half head: leaf 64 / leaf 96
        s.mS5 = s.pos;
        f5(s); s.mS4 = s.pos;
        f4(s); s.mS3 = s.pos;
        f3r(s); f2(s);
        { const float l0 = cnop(s.R1[0], s.R1[1]); leafR<0, 1>(s, l0, h); }
        oddL<1>(s, h);
        pairs<2>(s, h);
        if (h == 0) { s.uhPrev = s.uhCur; s.uhCur = 0; }
    }

    // best path = rank 0 (4 row-replica lanes have rF==0; take the first)
    const ull m = __ballot(s.rF == 0);
    const int bl = (int)__builtin_ctzll(m);
    const u32 b0 = (u32)__builtin_amdgcn_readlane((int)s.uhPrev, bl);
    const u32 b1 = (u32)__builtin_amdgcn_readlane((int)s.uhCur, bl);
    const u32 bits = (lane < 32) ? b0 : b1;
    out[(size_t)blockIdx.x * 64 + lane] = (float)((bits >> (lane & 31)) & 1u);
}

extern "C" void kernel_launch(void* const* d_in, const int* in_sizes, int n_in,
                              void* d_out, int out_size, void* d_ws, size_t ws_size,
                              hipStream_t stream) {
    (void)n_in; (void)out_size; (void)d_ws; (void)ws_size;
    const float* in = (const float*)d_in[0];
    float* out = (float*)d_out;
    const int batch = in_sizes[0] / 128;  // 2048
    scl_kernel<<<dim3(batch), dim3(64), 0, stream>>>(in, out);
}

// Round 13
// 55.412 us; speedup vs baseline: 1.0708x; 1.0708x over previous
//
#include <hip/hip_runtime.h>
#include <math.h>

#define LMAX 30.0f
typedef unsigned long long ull;
typedef unsigned int u32;

__device__ __forceinline__ float clip30(float x) { return fminf(fmaxf(x, -LMAX), LMAX); }
__device__ __forceinline__ float cnop(float x, float y) {
    x = clip30(x); y = clip30(y);
    const float m = fminf(fabsf(x), fabsf(y));
    const unsigned sg = (__float_as_uint(x) ^ __float_as_uint(y)) & 0x80000000u;
    return __uint_as_float(__float_as_uint(m) | sg);
}

#define SWZF(x, PAT) __int_as_float(__builtin_amdgcn_ds_swizzle(__float_as_int(x), (PAT)))

template<int CTRL>
__device__ __forceinline__ int dppi(int x) {
    return __builtin_amdgcn_update_dpp(x, x, CTRL, 0xF, 0xF, false);
}
template<int CTRL>
__device__ __forceinline__ float dppf(float x) {
    return __int_as_float(dppi<CTRL>(__float_as_int(x)));
}
#define CTL_XOR8 0x128  /* row_ror:8 == xor-8 within 16-lane rows */
#define CTL_XOR2 0x4E   /* quad_perm [2,3,0,1] */
#define CTL_XOR1 0xB1   /* quad_perm [1,0,3,2] */

#if __has_builtin(__builtin_amdgcn_permlane16_swap)
typedef int v2j_ __attribute__((ext_vector_type(2)));
__device__ __forceinline__ int swap16i(int x) {
    v2j_ r = __builtin_amdgcn_permlane16_swap(x, x, false, false);
    return (r[0] != x) ? r[0] : r[1];
}
#else
__device__ __forceinline__ int swap16i(int x) { return __builtin_amdgcn_ds_swizzle(x, 0x401F); }
#endif
__device__ __forceinline__ float swap16f(float x) { return __int_as_float(swap16i(__float_as_int(x))); }

__device__ __forceinline__ float gfb(float v, int a) {
    return __int_as_float(__builtin_amdgcn_ds_bpermute(a, __float_as_int(v)));
}
__device__ __forceinline__ u32 gub(u32 v, int a) {
    return (u32)__builtin_amdgcn_ds_bpermute(a, (int)v);
}

// polar encode folds
__device__ __forceinline__ u32 enc2(u32 w)  { w ^= (w >> 1) & 0x1u; return w; }
__device__ __forceinline__ u32 enc4(u32 w)  { w ^= (w >> 1) & 0x5u; w ^= (w >> 2) & 0x3u; return w; }
__device__ __forceinline__ u32 enc8(u32 w)  { w ^= (w >> 1) & 0x55u; w ^= (w >> 2) & 0x33u;
                                              w ^= (w >> 4) & 0x0fu; return w; }
__device__ __forceinline__ u32 enc16(u32 w) { w ^= (w >> 1) & 0x5555u; w ^= (w >> 2) & 0x3333u;
                                              w ^= (w >> 4) & 0x0f0fu; w ^= (w >> 8) & 0x00ffu; return w; }
__device__ __forceinline__ u32 enc32(u32 w) { w ^= (w >> 1) & 0x55555555u; w ^= (w >> 2) & 0x33333333u;
                                              w ^= (w >> 4) & 0x0f0f0f0fu; w ^= (w >> 8) & 0x00ff00ffu;
                                              w ^= (w >> 16) & 0x0000ffffu; return w; }

// ---- 2 decoders/wave; pos = lane&15, row q = (lane>>4)&1.
// Distributed over rows (stride 2): C[32], S5[16], S4[8], S3[4].
// Replicated per row: R2[4], R1[2]. uhat: u32 per 32-leaf half.
// S3/S4/S5 cloned via 1-word source maps (deferred, applied at read).
// Rank: full 15-compare DPP network (VALU only, no DS).
struct Dec {
    float C[32];
    float S5[16], S4[8], S3[4], R2[4], R1[2];
    float pm, su, df;
    u32 uhPrev, uhCur;
    int rF;
    int mS5, mS4, mS3;
    int q, pos, gbase;
    u32 upB;
    bool isUp;
    int tb[16];   // hoisted tie-break bools: position reached by ror:k is < pos
};

// hoist tie masks once: tb[k] = (pos_of(ror_k) < pos)
template<int K> __device__ __forceinline__ void tbInit(Dec& s) {
    const int jp = dppi<0x120 + K>(s.pos);
    s.tb[K] = (jp < s.pos) ? 1 : 0;
    if constexpr (K + 1 < 16) tbInit<K + 1>(s);
}
// full stable rank: compare vs all 15 other positions in-register
template<int K> __device__ __forceinline__ void rankStep(const Dec& s, const u32 pmB, int& r) {
    const u32 pmk = (u32)dppi<0x120 + K>((int)pmB);
    r += (pmk < pmB) ? 1 : 0;
    r += ((pmk == pmB) && s.tb[K]) ? 1 : 0;
    if constexpr (K + 1 < 16) rankStep<K + 1>(s, pmB, r);
}

__device__ __forceinline__ void f6(Dec& s) {
    #pragma unroll
    for (int k = 0; k < 16; ++k) s.S5[k] = cnop(s.C[k], s.C[k + 16]);
}
__device__ __forceinline__ void g6p(Dec& s) {   // head of half 1
    const u32 ub = enc32(s.uhPrev);
    #pragma unroll
    for (int k = 0; k < 16; ++k) {
        const int u = (ub >> (s.q + 2 * k)) & 1;
        s.S5[k] = u ? (s.C[k + 16] - s.C[k]) : (s.C[k + 16] + s.C[k]);
    }
}
__device__ __forceinline__ void f5(Dec& s) {
    #pragma unroll
    for (int k = 0; k < 8; ++k) s.S4[k] = cnop(s.S5[k], s.S5[k + 8]);
}
// L == 16 only: deferred S5 read through mS5; writes S4 fresh
__device__ __forceinline__ void g5l16(Dec& s) {
    const u32 ub = enc16(s.uhCur & 0xffffu);
    const int am = (s.mS5 | s.gbase) << 2;
    #pragma unroll
    for (int k = 0; k < 8; ++k) {
        const float x = gfb(s.S5[k], am), y = gfb(s.S5[k + 8], am);
        const int u = (ub >> (s.q + 2 * k)) & 1;
        s.S4[k] = u ? (y - x) : (y + x);
    }
    s.mS4 = s.pos;
}
__device__ __forceinline__ void f4(Dec& s) {
    #pragma unroll
    for (int k = 0; k < 4; ++k) s.S3[k] = cnop(s.S4[k], s.S4[k + 4]);
}
// L in {8,24}: deferred S4 read; writes S3 fresh
template<int L> __device__ __forceinline__ void g4l(Dec& s) {
    const u32 ub = enc8((s.uhCur >> (L - 8)) & 0xffu);
    const int am = (s.mS4 | s.gbase) << 2;
    #pragma unroll
    for (int k = 0; k < 4; ++k) {
        const float x = gfb(s.S4[k], am), y = gfb(s.S4[k + 4], am);
        const int u = (ub >> (s.q + 2 * k)) & 1;
        s.S3[k] = u ? (y - x) : (y + x);
    }
    s.mS3 = s.pos;
}
__device__ __forceinline__ void repl2(Dec& s, float t0, float t1) {
    const float P0 = swap16f(t0), P1 = swap16f(t1);
    s.R2[0] = s.q ? P0 : t0; s.R2[1] = s.q ? t0 : P0;
    s.R2[2] = s.q ? P1 : t1; s.R2[3] = s.q ? t1 : P1;
}
__device__ __forceinline__ void f3r(Dec& s) {
    repl2(s, cnop(s.S3[0], s.S3[2]), cnop(s.S3[1], s.S3[3]));
}
// L in {4,12,20,28}: deferred S3 read
template<int L> __device__ __forceinline__ void g3rl(Dec& s) {
    const u32 ub = enc4((s.uhCur >> (L - 4)) & 0xfu);
    const int am = (s.mS3 | s.gbase) << 2;
    const float x0 = gfb(s.S3[0], am), x1 = gfb(s.S3[1], am);
    const float x2 = gfb(s.S3[2], am), x3 = gfb(s.S3[3], am);
    const int u0 = (ub >> s.q) & 1, u1 = (ub >> (s.q + 2)) & 1;
    repl2(s, u0 ? (x2 - x0) : (x2 + x0), u1 ? (x3 - x1) : (x3 + x1));
}
__device__ __forceinline__ void f2(Dec& s) {
    s.R1[0] = cnop(s.R2[0], s.R2[2]); s.R1[1] = cnop(s.R2[1], s.R2[3]);
}
template<int L> __device__ __forceinline__ void g2l(Dec& s) {
    const u32 ub = enc2((s.uhCur >> (L - 2)) & 3u);
    s.R1[0] = (ub & 1) ? (s.R2[2] - s.R2[0]) : (s.R2[2] + s.R2[0]);
    s.R1[1] = (ub & 2) ? (s.R2[3] - s.R2[1]) : (s.R2[3] + s.R2[1]);
}

// leaf: decision + pm + DPP rank (no DS) + ballot-derived clone source +
// clone (pm/uh/su-df direct, R2 direct, maps for S3/S4/S5).
template<int L, int CLONEMODE>   // 0 never, 1 always, 2 only h==0
__device__ __forceinline__ void leafR(Dec& s, float l0, int h) {
    s.uhCur |= s.upB << L;
    const float l = clip30(l0);
    const float tail = log1pf(expf(-fabsf(l)));
    s.pm += (s.isUp ? fmaxf(l, 0.0f) : fmaxf(-l, 0.0f)) + tail;
    int r = 0;
    rankStep<1>(s, __float_as_uint(s.pm), r);
    s.rF = r;
    if constexpr (CLONEMODE != 0) {
        if (CLONEMODE == 1 || h == 0) {
            // src = position holding rank (pos&7): 8 uniform ballots + select
            const ull b0 = __ballot(r == 0), b1 = __ballot(r == 1);
            const ull b2 = __ballot(r == 2), b3 = __ballot(r == 3);
            const ull b4 = __ballot(r == 4), b5 = __ballot(r == 5);
            const ull b6 = __ballot(r == 6), b7 = __ballot(r == 7);
            const ull t0 = (s.pos & 1) ? b1 : b0;
            const ull t1 = (s.pos & 1) ? b3 : b2;
            const ull t2 = (s.pos & 1) ? b5 : b4;
            const ull t3 = (s.pos & 1) ? b7 : b6;
            const ull u0 = (s.pos & 2) ? t1 : t0;
            const ull u1 = (s.pos & 2) ? t3 : t2;
            const ull bb = (s.pos & 4) ? u1 : u0;
            const u32 win = (u32)(bb >> s.gbase) & 0xFFFFu;
            const int ga = (((int)__builtin_ctz(win)) | s.gbase) << 2;
            s.pm = gfb(s.pm, ga);
            s.uhCur = gub(s.uhCur, ga);
            if (h != 0) s.uhPrev = gub(s.uhPrev, ga);
            if constexpr ((L & 1) == 0) {
                // odd-leaf l0 candidates, adds off-chain, gathers batched
                s.su = gfb(s.R1[1] + s.R1[0], ga);
                s.df = gfb(s.R1[1] - s.R1[0], ga);
            }
            if constexpr ((L & 2) == 0) {
                #pragma unroll
                for (int e = 0; e < 4; ++e) s.R2[e] = gfb(s.R2[e], ga);
            }
            if constexpr ((L & 4) == 0) s.mS3 = __builtin_amdgcn_ds_bpermute(ga, s.mS3);
            if constexpr ((L & 8) == 0) s.mS4 = __builtin_amdgcn_ds_bpermute(ga, s.mS4);
            if constexpr ((L & 16) == 0) s.mS5 = __builtin_amdgcn_ds_bpermute(ga, s.mS5);
        }
    }
}

template<int J> __device__ __forceinline__ void evenL(Dec& s, int h) {
    constexpr int t = __builtin_ctz(J);   // J even, 2..30 -> t in 1..4
    if constexpr (t == 4) { g5l16(s); f4(s); s.mS3 = s.pos; }
    if constexpr (t == 3) { g4l<J>(s); }
    if constexpr (t >= 3) { f3r(s); }
    if constexpr (t == 2) { g3rl<J>(s); }
    if constexpr (t >= 2) { f2(s); }
    if constexpr (t == 1) { g2l<J>(s); }
    const float l0 = cnop(s.R1[0], s.R1[1]);
    leafR<J, 1>(s, l0, h);
}
template<int J> __device__ __forceinline__ void oddL(Dec& s, int h) {
    const int ug = (int)((s.uhCur >> (J - 1)) & 1u);
    const float l0 = ug ? s.df : s.su;
    leafR<J, (J == 31 ? 2 : 1)>(s, l0, h);
}
template<int J> __device__ __forceinline__ void pairs(Dec& s, int h) {
    evenL<J>(s, h);
    oddL<J + 1>(s, h);
    if constexpr (J + 2 <= 30) pairs<J + 2>(s, h);
}

#define RLF(x, J) __uint_as_float((u32)__builtin_amdgcn_readlane(__float_as_int(x), (J)))

__global__ __launch_bounds__(64) void scl_kernel(const float* __restrict__ in,
                                                 float* __restrict__ out) {
    __shared__ float chS[128];
    const int lane = threadIdx.x;
    const int w = lane & 31;
    const int d = lane >> 5;
    const int dbase = lane & 32;

    Dec s;
    s.pos = lane & 15;
    s.q = (lane >> 4) & 1;
    s.gbase = lane & 48;
    s.isUp = (lane & 8) != 0;
    s.upB = (u32)((lane >> 3) & 1);
    s.uhPrev = 0; s.uhCur = 0; s.rF = 0;
    tbInit<1>(s);

    const size_t base = ((size_t)blockIdx.x * 2 + d) * 128;
    const float a1 = -in[base + w],      c1 = -in[base + 64 + w];
    const float a2 = -in[base + 32 + w], c2 = -in[base + 96 + w];
    chS[d * 64 + w] = a1 + c1;            // stage-6 right-subtree llr (u=0 g)
    chS[d * 64 + 32 + w] = a2 + c2;
    __syncthreads();
    #pragma unroll
    for (int k = 0; k < 32; ++k) s.C[k] = chS[d * 64 + s.q + 2 * k];

    // ---- frozen half (leaves 0..63): all paths identical, u == 0; butterfly
    float v1 = cnop(a1, c1), v2 = cnop(a2, c2);
    { const float n1 = cnop(v1, v2); v2 = v1 + v2; v1 = n1; }             // h=32
    { const float o1 = swap16f(v1), o2 = swap16f(v2);                      // h=16
      v1 = (w & 16) ? (o1 + v1) : cnop(v1, o1);
      v2 = (w & 16) ? (o2 + v2) : cnop(v2, o2); }
    { const float o1 = dppf<CTL_XOR8>(v1), o2 = dppf<CTL_XOR8>(v2);        // h=8
      v1 = (w & 8) ? (o1 + v1) : cnop(v1, o1);
      v2 = (w & 8) ? (o2 + v2) : cnop(v2, o2); }
    { const float o1 = SWZF(v1, 0x101F), o2 = SWZF(v2, 0x101F);            // h=4
      v1 = (w & 4) ? (o1 + v1) : cnop(v1, o1);
      v2 = (w & 4) ? (o2 + v2) : cnop(v2, o2); }
    { const float o1 = dppf<CTL_XOR2>(v1), o2 = dppf<CTL_XOR2>(v2);        // h=2
      v1 = (w & 2) ? (o1 + v1) : cnop(v1, o1);
      v2 = (w & 2) ? (o2 + v2) : cnop(v2, o2); }
    { const float o1 = dppf<CTL_XOR1>(v1), o2 = dppf<CTL_XOR1>(v2);        // h=1
      v1 = (w & 1) ? (o1 + v1) : cnop(v1, o1);
      v2 = (w & 1) ? (o2 + v2) : cnop(v2, o2); }
    const float sp1 = fmaxf(-clip30(v1), 0.0f) + log1pf(expf(-fabsf(clip30(v1))));
    const float sp2 = fmaxf(-clip30(v2), 0.0f) + log1pf(expf(-fabsf(clip30(v2))));

    // exact sequential pm accumulation per decoder (reference FP order)
    s.pm = ((s.pos == 0) || (s.pos == 8)) ? 0.0f : LMAX;
    if (lane < 32) {
        #pragma unroll
        for (int j = 0; j < 32; ++j) s.pm += RLF(sp1, j);
        #pragma unroll
        for (int j = 0; j < 32; ++j) s.pm += RLF(sp2, j);
    } else {
        #pragma unroll
        for (int j = 32; j < 64; ++j) s.pm += RLF(sp1, j);
        #pragma unroll
        for (int j = 32; j < 64; ++j) s.pm += RLF(sp2, j);
    }

    // ---- info half: two 32-leaf halves sharing one unrolled body ----
    #pragma unroll 1
    for (int h = 0; h < 2; ++h) {
        if (h == 0) f6(s); else g6p(s);    // half head: leaf 64 / leaf 96
        s.mS5 = s.pos;
        f5(s); s.mS4 = s.pos;
        f4(s); s.mS3 = s.pos;
        f3r(s); f2(s);
        { const float l0 = cnop(s.R1[0], s.R1[1]); leafR<0, 1>(s, l0, h); }
        oddL<1>(s, h);
        pairs<2>(s, h);
        if (h == 0) { s.uhPrev = s.uhCur; s.uhCur = 0; }
    }

    // best path per decoder = rank 0; fetch its uh words
    const ull m = __ballot(s.rF == 0);
    const int bl = dbase + (int)__builtin_ctz((u32)(m >> dbase));
    const u32 b0 = gub(s.uhPrev, bl << 2);   // info bits 0..31  (leaves 64..95)
    const u32 b1 = gub(s.uhCur, bl << 2);    // info bits 32..63 (leaves 96..127)
    const size_t ob = ((size_t)blockIdx.x * 2 + d) * 64;
    out[ob + w] = (float)((b0 >> w) & 1u);
    out[ob + 32 + w] = (float)((b1 >> w) & 1u);
}

extern "C" void kernel_launch(void* const* d_in, const int* in_sizes, int n_in,
                              void* d_out, int out_size, void* d_ws, size_t ws_size,
                              hipStream_t stream) {
    (void)n_in; (void)out_size; (void)d_ws; (void)ws_size;
    const float* in = (const float*)d_in[0];
    float* out = (float*)d_out;
    const int batch = in_sizes[0] / 128;  // 2048
    scl_kernel<<<dim3(batch / 2), dim3(64), 0, stream>>>(in, out);
}

// Round 14
// 51.896 us; speedup vs baseline: 1.1433x; 1.0677x over previous
//
#include <hip/hip_runtime.h>
#include <math.h>

#define LMAX 30.0f
typedef unsigned long long ull;
typedef unsigned int u32;

__device__ __forceinline__ float clip30(float x) { return fminf(fmaxf(x, -LMAX), LMAX); }
__device__ __forceinline__ float cnop(float x, float y) {
    x = clip30(x); y = clip30(y);
    const float m = fminf(fabsf(x), fabsf(y));
    const unsigned sg = (__float_as_uint(x) ^ __float_as_uint(y)) & 0x80000000u;
    return __uint_as_float(__float_as_uint(m) | sg);
}

#define SWZF(x, PAT) __int_as_float(__builtin_amdgcn_ds_swizzle(__float_as_int(x), (PAT)))

template<int CTRL>
__device__ __forceinline__ int dppi(int x) {
    return __builtin_amdgcn_update_dpp(x, x, CTRL, 0xF, 0xF, false);
}
template<int CTRL>
__device__ __forceinline__ float dppf(float x) {
    return __int_as_float(dppi<CTRL>(__float_as_int(x)));
}
#define CTL_XOR8 0x128  /* row_ror:8 == xor-8 within 16-lane rows */
#define CTL_XOR2 0x4E   /* quad_perm [2,3,0,1] */
#define CTL_XOR1 0xB1   /* quad_perm [1,0,3,2] */

#if __has_builtin(__builtin_amdgcn_permlane16_swap)
typedef int v2j_ __attribute__((ext_vector_type(2)));
__device__ __forceinline__ int swap16i(int x) {
    v2j_ r = __builtin_amdgcn_permlane16_swap(x, x, false, false);
    return (r[0] != x) ? r[0] : r[1];
}
#else
__device__ __forceinline__ int swap16i(int x) { return __builtin_amdgcn_ds_swizzle(x, 0x401F); }
#endif
__device__ __forceinline__ float swap16f(float x) { return __int_as_float(swap16i(__float_as_int(x))); }

__device__ __forceinline__ float gfb(float v, int a) {
    return __int_as_float(__builtin_amdgcn_ds_bpermute(a, __float_as_int(v)));
}
__device__ __forceinline__ u32 gub(u32 v, int a) {
    return (u32)__builtin_amdgcn_ds_bpermute(a, (int)v);
}

// polar encode folds
__device__ __forceinline__ u32 enc2(u32 w)  { w ^= (w >> 1) & 0x1u; return w; }
__device__ __forceinline__ u32 enc4(u32 w)  { w ^= (w >> 1) & 0x5u; w ^= (w >> 2) & 0x3u; return w; }
__device__ __forceinline__ u32 enc8(u32 w)  { w ^= (w >> 1) & 0x55u; w ^= (w >> 2) & 0x33u;
                                              w ^= (w >> 4) & 0x0fu; return w; }
__device__ __forceinline__ u32 enc16(u32 w) { w ^= (w >> 1) & 0x5555u; w ^= (w >> 2) & 0x3333u;
                                              w ^= (w >> 4) & 0x0f0fu; w ^= (w >> 8) & 0x00ffu; return w; }
__device__ __forceinline__ u32 enc32(u32 w) { w ^= (w >> 1) & 0x55555555u; w ^= (w >> 2) & 0x33333333u;
                                              w ^= (w >> 4) & 0x0f0f0f0fu; w ^= (w >> 8) & 0x00ff00ffu;
                                              w ^= (w >> 16) & 0x0000ffffu; return w; }

// ---- 2 decoders/wave; pos = lane&15, row q = (lane>>4)&1.
// Distributed over rows (stride 2): C[32], S5[16], S4[8], S3[4].
// Replicated per row: R2[4], R1[2]. uhat: u32 per 32-leaf half.
// S3/S4/S5 cloned via 1-word source maps (deferred, applied at read).
// su/df: odd-leaf l0 candidates, computed pre-gather (off critical path).
struct Dec {
    float C[32];
    float S5[16], S4[8], S3[4], R2[4], R1[2];
    float pm, su, df;
    u32 uhPrev, uhCur;
    int rF;
    int mS5, mS4, mS3;
    int q, pos, gbase, A0, idx0;
    u32 upB;
    bool isUp;
};

__device__ __forceinline__ void f6(Dec& s) {
    #pragma unroll
    for (int k = 0; k < 16; ++k) s.S5[k] = cnop(s.C[k], s.C[k + 16]);
}
__device__ __forceinline__ void g6p(Dec& s) {   // head of half 1
    const u32 ub = enc32(s.uhPrev);
    #pragma unroll
    for (int k = 0; k < 16; ++k) {
        const int u = (ub >> (s.q + 2 * k)) & 1;
        s.S5[k] = u ? (s.C[k + 16] - s.C[k]) : (s.C[k + 16] + s.C[k]);
    }
}
__device__ __forceinline__ void f5(Dec& s) {
    #pragma unroll
    for (int k = 0; k < 8; ++k) s.S4[k] = cnop(s.S5[k], s.S5[k + 8]);
}
// L == 16 only: deferred S5 read through mS5; writes S4 fresh
__device__ __forceinline__ void g5l16(Dec& s) {
    const u32 ub = enc16(s.uhCur & 0xffffu);
    const int am = (s.mS5 | s.gbase) << 2;
    #pragma unroll
    for (int k = 0; k < 8; ++k) {
        const float x = gfb(s.S5[k], am), y = gfb(s.S5[k + 8], am);
        const int u = (ub >> (s.q + 2 * k)) & 1;
        s.S4[k] = u ? (y - x) : (y + x);
    }
    s.mS4 = s.pos;
}
__device__ __forceinline__ void f4(Dec& s) {
    #pragma unroll
    for (int k = 0; k < 4; ++k) s.S3[k] = cnop(s.S4[k], s.S4[k + 4]);
}
// L in {8,24}: deferred S4 read; writes S3 fresh
template<int L> __device__ __forceinline__ void g4l(Dec& s) {
    const u32 ub = enc8((s.uhCur >> (L - 8)) & 0xffu);
    const int am = (s.mS4 | s.gbase) << 2;
    #pragma unroll
    for (int k = 0; k < 4; ++k) {
        const float x = gfb(s.S4[k], am), y = gfb(s.S4[k + 4], am);
        const int u = (ub >> (s.q + 2 * k)) & 1;
        s.S3[k] = u ? (y - x) : (y + x);
    }
    s.mS3 = s.pos;
}
__device__ __forceinline__ void repl2(Dec& s, float t0, float t1) {
    const float P0 = swap16f(t0), P1 = swap16f(t1);
    s.R2[0] = s.q ? P0 : t0; s.R2[1] = s.q ? t0 : P0;
    s.R2[2] = s.q ? P1 : t1; s.R2[3] = s.q ? t1 : P1;
}
__device__ __forceinline__ void f3r(Dec& s) {
    repl2(s, cnop(s.S3[0], s.S3[2]), cnop(s.S3[1], s.S3[3]));
}
// L in {4,12,20,28}: deferred S3 read
template<int L> __device__ __forceinline__ void g3rl(Dec& s) {
    const u32 ub = enc4((s.uhCur >> (L - 4)) & 0xfu);
    const int am = (s.mS3 | s.gbase) << 2;
    const float x0 = gfb(s.S3[0], am), x1 = gfb(s.S3[1], am);
    const float x2 = gfb(s.S3[2], am), x3 = gfb(s.S3[3], am);
    const int u0 = (ub >> s.q) & 1, u1 = (ub >> (s.q + 2)) & 1;
    repl2(s, u0 ? (x2 - x0) : (x2 + x0), u1 ? (x3 - x1) : (x3 + x1));
}
__device__ __forceinline__ void f2(Dec& s) {
    s.R1[0] = cnop(s.R2[0], s.R2[2]); s.R1[1] = cnop(s.R2[1], s.R2[3]);
}
template<int L> __device__ __forceinline__ void g2l(Dec& s) {
    const u32 ub = enc2((s.uhCur >> (L - 2)) & 3u);
    s.R1[0] = (ub & 1) ? (s.R2[2] - s.R2[0]) : (s.R2[2] + s.R2[0]);
    s.R1[1] = (ub & 2) ? (s.R2[3] - s.R2[1]) : (s.R2[3] + s.R2[1]);
}

// leaf: decision + pm + distributed stable rank (8 keys/lane, swap16 reduce) +
// ballot-derived clone source + clone (pm/uh/su-df direct, R2 direct, maps).
template<int L, int CLONEMODE>   // 0 never, 1 always, 2 only h==0
__device__ __forceinline__ void leafR(Dec& s, float l0, int h) {
    s.uhCur |= s.upB << L;
    const float l = clip30(l0);
    const float tail = log1pf(expf(-fabsf(l)));
    s.pm += (s.isUp ? fmaxf(l, 0.0f) : fmaxf(-l, 0.0f)) + tail;
    int r = 0;
    {
        const u32 pmB = __float_as_uint(s.pm);
        #pragma unroll
        for (int k = 0; k < 8; ++k) {
            const u32 pmj = (u32)__builtin_amdgcn_ds_bpermute(s.A0 + 4 * k, __float_as_int(s.pm));
            r += ((pmj < pmB) || (pmj == pmB && (s.idx0 + k) < s.pos)) ? 1 : 0;
        }
    }
    r += swap16i(r);
    s.rF = r;
    if constexpr (CLONEMODE != 0) {
        if (CLONEMODE == 1 || h == 0) {
            // src = position holding rank (pos&7): 8 uniform ballots + select
            const ull b0 = __ballot(r == 0), b1 = __ballot(r == 1);
            const ull b2 = __ballot(r == 2), b3 = __ballot(r == 3);
            const ull b4 = __ballot(r == 4), b5 = __ballot(r == 5);
            const ull b6 = __ballot(r == 6), b7 = __ballot(r == 7);
            const ull t0 = (s.pos & 1) ? b1 : b0;
            const ull t1 = (s.pos & 1) ? b3 : b2;
            const ull t2 = (s.pos & 1) ? b5 : b4;
            const ull t3 = (s.pos & 1) ? b7 : b6;
            const ull u0 = (s.pos & 2) ? t1 : t0;
            const ull u1 = (s.pos & 2) ? t3 : t2;
            const ull bb = (s.pos & 4) ? u1 : u0;
            const u32 win = (u32)(bb >> s.gbase) & 0xFFFFu;
            const int ga = (((int)__builtin_ctz(win)) | s.gbase) << 2;
            s.pm = gfb(s.pm, ga);
            s.uhCur = gub(s.uhCur, ga);
            if (h != 0) s.uhPrev = gub(s.uhPrev, ga);
            if constexpr ((L & 1) == 0) {
                // odd-leaf l0 candidates: adds computed BEFORE gather
                s.su = gfb(s.R1[1] + s.R1[0], ga);
                s.df = gfb(s.R1[1] - s.R1[0], ga);
            }
            if constexpr ((L & 2) == 0) {
                #pragma unroll
                for (int e = 0; e < 4; ++e) s.R2[e] = gfb(s.R2[e], ga);
            }
            if constexpr ((L & 4) == 0) s.mS3 = __builtin_amdgcn_ds_bpermute(ga, s.mS3);
            if constexpr ((L & 8) == 0) s.mS4 = __builtin_amdgcn_ds_bpermute(ga, s.mS4);
            if constexpr ((L & 16) == 0) s.mS5 = __builtin_amdgcn_ds_bpermute(ga, s.mS5);
        }
    }
}

template<int J> __device__ __forceinline__ void evenL(Dec& s, int h) {
    constexpr int t = __builtin_ctz(J);   // J even, 2..30 -> t in 1..4
    if constexpr (t == 4) { g5l16(s); f4(s); s.mS3 = s.pos; }
    if constexpr (t == 3) { g4l<J>(s); }
    if constexpr (t >= 3) { f3r(s); }
    if constexpr (t == 2) { g3rl<J>(s); }
    if constexpr (t >= 2) { f2(s); }
    if constexpr (t == 1) { g2l<J>(s); }
    const float l0 = cnop(s.R1[0], s.R1[1]);
    leafR<J, 1>(s, l0, h);
}
template<int J> __device__ __forceinline__ void oddL(Dec& s, int h) {
    const int ug = (int)((s.uhCur >> (J - 1)) & 1u);
    const float l0 = ug ? s.df : s.su;
    leafR<J, (J == 31 ? 2 : 1)>(s, l0, h);
}
template<int J> __device__ __forceinline__ void pairs(Dec& s, int h) {
    evenL<J>(s, h);
    oddL<J + 1>(s, h);
    if constexpr (J + 2 <= 30) pairs<J + 2>(s, h);
}

#define RLF(x, J) __uint_as_float((u32)__builtin_amdgcn_readlane(__float_as_int(x), (J)))

__global__ __launch_bounds__(64) void scl_kernel(const float* __restrict__ in,
                                                 float* __restrict__ out) {
    __shared__ float chS[128];
    const int lane = threadIdx.x;
    const int w = lane & 31;
    const int d = lane >> 5;
    const int dbase = lane & 32;

    Dec s;
    s.pos = lane & 15;
    s.q = (lane >> 4) & 1;
    s.gbase = lane & 48;
    s.isUp = (lane & 8) != 0;
    s.upB = (u32)((lane >> 3) & 1);
    s.idx0 = s.q << 3;
    s.A0 = (dbase | (s.q << 3)) << 2;
    s.uhPrev = 0; s.uhCur = 0; s.rF = 0;

    const size_t base = ((size_t)blockIdx.x * 2 + d) * 128;
    const float a1 = -in[base + w],      c1 = -in[base + 64 + w];
    const float a2 = -in[base + 32 + w], c2 = -in[base + 96 + w];
    chS[d * 64 + w] = a1 + c1;            // stage-6 right-subtree llr (u=0 g)
    chS[d * 64 + 32 + w] = a2 + c2;
    __syncthreads();
    #pragma unroll
    for (int k = 0; k < 32; ++k) s.C[k] = chS[d * 64 + s.q + 2 * k];

    // ---- frozen half (leaves 0..63): all paths identical, u == 0; butterfly
    float v1 = cnop(a1, c1), v2 = cnop(a2, c2);
    { const float n1 = cnop(v1, v2); v2 = v1 + v2; v1 = n1; }             // h=32
    { const float o1 = swap16f(v1), o2 = swap16f(v2);                      // h=16
      v1 = (w & 16) ? (o1 + v1) : cnop(v1, o1);
      v2 = (w & 16) ? (o2 + v2) : cnop(v2, o2); }
    { const float o1 = dppf<CTL_XOR8>(v1), o2 = dppf<CTL_XOR8>(v2);        // h=8
      v1 = (w & 8) ? (o1 + v1) : cnop(v1, o1);
      v2 = (w & 8) ? (o2 + v2) : cnop(v2, o2); }
    { const float o1 = SWZF(v1, 0x101F), o2 = SWZF(v2, 0x101F);            // h=4
      v1 = (w & 4) ? (o1 + v1) : cnop(v1, o1);
      v2 = (w & 4) ? (o2 + v2) : cnop(v2, o2); }
    { const float o1 = dppf<CTL_XOR2>(v1), o2 = dppf<CTL_XOR2>(v2);        // h=2
      v1 = (w & 2) ? (o1 + v1) : cnop(v1, o1);
      v2 = (w & 2) ? (o2 + v2) : cnop(v2, o2); }
    { const float o1 = dppf<CTL_XOR1>(v1), o2 = dppf<CTL_XOR1>(v2);        // h=1
      v1 = (w & 1) ? (o1 + v1) : cnop(v1, o1);
      v2 = (w & 1) ? (o2 + v2) : cnop(v2, o2); }
    const float sp1 = fmaxf(-clip30(v1), 0.0f) + log1pf(expf(-fabsf(clip30(v1))));
    const float sp2 = fmaxf(-clip30(v2), 0.0f) + log1pf(expf(-fabsf(clip30(v2))));

    // exact sequential pm accumulation per decoder (reference FP order)
    s.pm = ((s.pos == 0) || (s.pos == 8)) ? 0.0f : LMAX;
    if (lane < 32) {
        #pragma unroll
        for (int j = 0; j < 32; ++j) s.pm += RLF(sp1, j);
        #pragma unroll
        for (int j = 0; j < 32; ++j) s.pm += RLF(sp2, j);
    } else {
        #pragma unroll
        for (int j = 32; j < 64; ++j) s.pm += RLF(sp1, j);
        #pragma unroll
        for (int j = 32; j < 64; ++j) s.pm += RLF(sp2, j);
    }

    // ---- info half: two 32-leaf halves sharing one unrolled body ----
    #pragma unroll 1
    for (int h = 0; h < 2; ++h) {
        if (h == 0) f6(s); else g6p(s);    // half head: leaf 64 / leaf 96
        s.mS5 = s.pos;
        f5(s); s.mS4 = s.pos;
        f4(s); s.mS3 = s.pos;
        f3r(s); f2(s);
        { const float l0 = cnop(s.R1[0], s.R1[1]); leafR<0, 1>(s, l0, h); }
        oddL<1>(s, h);
        pairs<2>(s, h);
        if (h == 0) { s.uhPrev = s.uhCur; s.uhCur = 0; }
    }

    // best path per decoder = rank 0; fetch its uh words
    const ull m = __ballot(s.rF == 0);
    const int bl = dbase + (int)__builtin_ctz((u32)(m >> dbase));
    const u32 b0 = gub(s.uhPrev, bl << 2);   // info bits 0..31  (leaves 64..95)
    const u32 b1 = gub(s.uhCur, bl << 2);    // info bits 32..63 (leaves 96..127)
    const size_t ob = ((size_t)blockIdx.x * 2 + d) * 64;
    out[ob + w] = (float)((b0 >> w) & 1u);
    out[ob + 32 + w] = (float)((b1 >> w) & 1u);
}

extern "C" void kernel_launch(void* const* d_in, const int* in_sizes, int n_in,
                              void* d_out, int out_size, void* d_ws, size_t ws_size,
                              hipStream_t stream) {
    (void)n_in; (void)out_size; (void)d_ws; (void)ws_size;
    const float* in = (const float*)d_in[0];
    float* out = (float*)d_out;
    const int batch = in_sizes[0] / 128;  // 2048
    scl_kernel<<<dim3(batch / 2), dim3(64), 0, stream>>>(in, out);
}